// Round 4
// baseline (83.676 us; speedup 1.0000x reference)
//
#include <hip/hip_runtime.h>

// CenterLoss: loss = ( sum_i |x_i - c_{label_i}|^2  +  B*(C-1)*1e-12 ) / B
// B=16384, C=1000, D=512.
//
// v5: attack the post-fill cache state, not the kernel structure.
//
// Component fit across rounds 0-3:
//   poison fill 44us | stage1 work W ~26us | stage2 ~2us | graph overhead ~7us
//   (v2 kernel = W+A+R = 84us direct-measured; A(same-addr atomics) ~22us from
//    v3-v4 totals; R(ACQ_REL L2 maintenance) ~36us from v1-v3 totals.)
//   W is structure-insensitive: v0 (1024 blk, looped) == v4 (2048 blk, flat).
//
// Theory: the harness's 268MB workspace poison fill immediately precedes
// stage1 and leaves the 256MB memory-side L3 (+32MB of L2s) full of DIRTY
// poison. Stage1's x read-misses each force a dirty-line eviction while the
// MALL drains the rest -> reads contend with a saturated writeback path ->
// effective read BW ~1TB/s (24MB/26us), VALUBusy ~3%, nothing busy.
//
// Fix: NON-TEMPORAL loads for x (streamed once, zero reuse). nt misses do
// not allocate in L2/L3 -> no forced dirty-poison evictions, no pollution of
// the L2 space the centers gather wants. Centers stay temporal (2MB, reused
// ~16x per XCD, L2-resident).
//
// Kept from v4: per-lane accumulation (per-row clamp dropped: d^2~N(1024,64),
// even d^2==0 shifts loss by 6e-17, invisible at fp32 ulp 6e-5), 2 rows/wave
// with all 16 loads batched, one shuffle chain per wave, two-dispatch
// structure with plain partial stores (atomics measured 22us slower).

#define B_ROWS    16384
#define C_CLASSES 1000
#define D_DIM     512
#define S1_BLOCKS 2048          // 2048 blocks * 4 waves * 2 rows = 16384 rows

typedef float f4 __attribute__((ext_vector_type(4)));

__global__ __launch_bounds__(256) void center_loss_stage1(
    const float* __restrict__ x,
    const int*   __restrict__ labels,
    const float* __restrict__ centers,
    float*       __restrict__ partials)
{
    const int tid  = threadIdx.x;
    const int wave = tid >> 6;
    const int lane = tid & 63;
    const int row0 = (blockIdx.x * 4 + wave) * 2;   // 2 consecutive rows/wave

    // labels head the dependent gather chain -- issue first
    const int lab0 = labels[row0];
    const int lab1 = labels[row0 + 1];

    const f4* __restrict__ xr0 = (const f4*)(x + (size_t)row0 * D_DIM);
    const f4* __restrict__ xr1 = (const f4*)(x + (size_t)(row0 + 1) * D_DIM);
    const f4* __restrict__ cr0 = (const f4*)(centers + (size_t)lab0 * D_DIM);
    const f4* __restrict__ cr1 = (const f4*)(centers + (size_t)lab1 * D_DIM);

    // x: non-temporal (streamed once; don't allocate in L2/L3, don't force
    // dirty-poison evictions). centers: temporal (reused, want L2).
    f4 xa0 = __builtin_nontemporal_load(xr0 + lane);
    f4 xb0 = __builtin_nontemporal_load(xr0 + lane + 64);
    f4 xa1 = __builtin_nontemporal_load(xr1 + lane);
    f4 xb1 = __builtin_nontemporal_load(xr1 + lane + 64);
    f4 ca0 = cr0[lane];
    f4 cb0 = cr0[lane + 64];
    f4 ca1 = cr1[lane];
    f4 cb1 = cr1[lane + 64];

    float acc;
    {
        float d0 = xa0.x - ca0.x, d1 = xa0.y - ca0.y;
        float d2 = xa0.z - ca0.z, d3 = xa0.w - ca0.w;
        float e0 = xb0.x - cb0.x, e1 = xb0.y - cb0.y;
        float e2 = xb0.z - cb0.z, e3 = xb0.w - cb0.w;
        acc = d0*d0 + d1*d1 + d2*d2 + d3*d3
            + e0*e0 + e1*e1 + e2*e2 + e3*e3;
    }
    {
        float d0 = xa1.x - ca1.x, d1 = xa1.y - ca1.y;
        float d2 = xa1.z - ca1.z, d3 = xa1.w - ca1.w;
        float e0 = xb1.x - cb1.x, e1 = xb1.y - cb1.y;
        float e2 = xb1.z - cb1.z, e3 = xb1.w - cb1.w;
        acc += d0*d0 + d1*d1 + d2*d2 + d3*d3
             + e0*e0 + e1*e1 + e2*e2 + e3*e3;
    }

    // wave-64 reduction (once per wave, off the load path)
    #pragma unroll
    for (int off = 32; off > 0; off >>= 1)
        acc += __shfl_down(acc, off, 64);

    __shared__ float wsum[4];
    if (lane == 0) wsum[wave] = acc;
    __syncthreads();

    if (tid == 0)
        partials[blockIdx.x] = wsum[0] + wsum[1] + wsum[2] + wsum[3];
}

__global__ __launch_bounds__(256) void center_loss_stage2(
    const float* __restrict__ partials,
    float*       __restrict__ out)
{
    const int tid  = threadIdx.x;
    const int wave = tid >> 6;
    const int lane = tid & 63;

    // 2048 partials = 512 float4; 256 threads x 2 float4
    const f4* __restrict__ p4 = (const f4*)partials;
    f4 a = p4[tid];
    f4 b = p4[tid + 256];
    float s = a.x + a.y + a.z + a.w + b.x + b.y + b.z + b.w;

    #pragma unroll
    for (int off = 32; off > 0; off >>= 1)
        s += __shfl_down(s, off, 64);

    __shared__ float lds[4];
    if (lane == 0) lds[wave] = s;
    __syncthreads();
    if (tid == 0) {
        float tot = lds[0] + lds[1] + lds[2] + lds[3];
        // masked-out zeros clamp up to 1e-12 in the reference: B*(C-1) of them
        tot += (float)B_ROWS * (float)(C_CLASSES - 1) * 1e-12f;
        out[0] = tot / (float)B_ROWS;
    }
}

extern "C" void kernel_launch(void* const* d_in, const int* in_sizes, int n_in,
                              void* d_out, int out_size, void* d_ws, size_t ws_size,
                              hipStream_t stream) {
    const float* x       = (const float*)d_in[0];
    const int*   labels  = (const int*)d_in[1];
    const float* centers = (const float*)d_in[2];
    float*       out     = (float*)d_out;
    float*       partials = (float*)d_ws;   // S1_BLOCKS floats = 8 KB

    center_loss_stage1<<<S1_BLOCKS, 256, 0, stream>>>(x, labels, centers, partials);
    center_loss_stage2<<<1, 256, 0, stream>>>(partials, out);
}

// Round 5
// 79.037 us; speedup vs baseline: 1.0587x; 1.0587x over previous
//
#include <hip/hip_runtime.h>

// CenterLoss: loss = ( sum_i |x_i - c_{label_i}|^2  +  B*(C-1)*1e-12 ) / B
// B=16384, C=1000, D=512.
//
// v6 == v4 (session best, 79.2us): pure revert of v5's non-temporal loads.
//
// FINAL MODEL (rounds 0-4):
//   timed region = 44us harness poison fill (268MB @ 6.2TB/s, 78% HBM peak)
//                + ~26us stage1 + ~2us stage2 + ~5-7us graph node gaps.
//   stage1's 26us is NOT kernel-limited: the poison fill sweeps the 256MB
//   MALL with dirty lines every iteration, so stage1's 33.5MB of x reads
//   each force a dirty-line writeback (~67MB interleaved R+W at degraded
//   HBM efficiency). Evidence: W identical across 3 structural variants
//   (1024-blk looped / 2048-blk flat / NT loads), no pipe >4% busy, and
//   nontemporal loads are null (nt is a CU-side hint; MALL is memory-side).
//   Kernel-side levers exhausted; remaining controllable slack ~2-4us (<5%).
//
// Failure ledger (measured, do not repeat):
//   v2: per-block ACQ_REL agent atomics -> +36us (L2 writeback/inv per block)
//   v3: 2048 same-address RMW atomics on out[0] -> +22us (serialized tail)
//   v5: nontemporal x loads -> +4.5us (loses L2 allocation, MALL unaffected)
//
// Structure: two dispatches. Stage1: 2048 blocks x 4 waves x 2 rows; per-row
// clamp(d^2,1e-12,1e12) dropped (d^2~N(1024,64); even d^2==0 shifts the loss
// by 1e-12/B ~ 6e-17, invisible at fp32 ulp ~6e-5 of the ~1022 result); all
// 16 float4 loads per wave issued as one independent batch; one shuffle
// chain per wave; plain per-block partial stores (distinct addresses, zero
// contention, end-of-dispatch release). Stage2: one block reduces 2048
// partials and applies the B*(C-1)*1e-12 masked-zero clamp term.

#define B_ROWS    16384
#define C_CLASSES 1000
#define D_DIM     512
#define S1_BLOCKS 2048          // 2048 blocks * 4 waves * 2 rows = 16384 rows

typedef float f4 __attribute__((ext_vector_type(4)));

__global__ __launch_bounds__(256) void center_loss_stage1(
    const float* __restrict__ x,
    const int*   __restrict__ labels,
    const float* __restrict__ centers,
    float*       __restrict__ partials)
{
    const int tid  = threadIdx.x;
    const int wave = tid >> 6;
    const int lane = tid & 63;
    const int row0 = (blockIdx.x * 4 + wave) * 2;   // 2 consecutive rows/wave

    // labels head the dependent gather chain -- issue first
    const int lab0 = labels[row0];
    const int lab1 = labels[row0 + 1];

    const f4* __restrict__ xr0 = (const f4*)(x + (size_t)row0 * D_DIM);
    const f4* __restrict__ xr1 = (const f4*)(x + (size_t)(row0 + 1) * D_DIM);
    const f4* __restrict__ cr0 = (const f4*)(centers + (size_t)lab0 * D_DIM);
    const f4* __restrict__ cr1 = (const f4*)(centers + (size_t)lab1 * D_DIM);

    // 512 floats = 128 float4 per row; 64 lanes x 2 coalesced float4 per row.
    // All 16 loads mutually independent -> deep memory-level parallelism.
    f4 xa0 = xr0[lane];
    f4 xb0 = xr0[lane + 64];
    f4 xa1 = xr1[lane];
    f4 xb1 = xr1[lane + 64];
    f4 ca0 = cr0[lane];
    f4 cb0 = cr0[lane + 64];
    f4 ca1 = cr1[lane];
    f4 cb1 = cr1[lane + 64];

    float acc;
    {
        float d0 = xa0.x - ca0.x, d1 = xa0.y - ca0.y;
        float d2 = xa0.z - ca0.z, d3 = xa0.w - ca0.w;
        float e0 = xb0.x - cb0.x, e1 = xb0.y - cb0.y;
        float e2 = xb0.z - cb0.z, e3 = xb0.w - cb0.w;
        acc = d0*d0 + d1*d1 + d2*d2 + d3*d3
            + e0*e0 + e1*e1 + e2*e2 + e3*e3;
    }
    {
        float d0 = xa1.x - ca1.x, d1 = xa1.y - ca1.y;
        float d2 = xa1.z - ca1.z, d3 = xa1.w - ca1.w;
        float e0 = xb1.x - cb1.x, e1 = xb1.y - cb1.y;
        float e2 = xb1.z - cb1.z, e3 = xb1.w - cb1.w;
        acc += d0*d0 + d1*d1 + d2*d2 + d3*d3
             + e0*e0 + e1*e1 + e2*e2 + e3*e3;
    }

    // wave-64 reduction (once per wave, off the load path)
    #pragma unroll
    for (int off = 32; off > 0; off >>= 1)
        acc += __shfl_down(acc, off, 64);

    __shared__ float wsum[4];
    if (lane == 0) wsum[wave] = acc;
    __syncthreads();

    if (tid == 0)
        partials[blockIdx.x] = wsum[0] + wsum[1] + wsum[2] + wsum[3];
}

__global__ __launch_bounds__(256) void center_loss_stage2(
    const float* __restrict__ partials,
    float*       __restrict__ out)
{
    const int tid  = threadIdx.x;
    const int wave = tid >> 6;
    const int lane = tid & 63;

    // 2048 partials = 512 float4; 256 threads x 2 float4
    const f4* __restrict__ p4 = (const f4*)partials;
    f4 a = p4[tid];
    f4 b = p4[tid + 256];
    float s = a.x + a.y + a.z + a.w + b.x + b.y + b.z + b.w;

    #pragma unroll
    for (int off = 32; off > 0; off >>= 1)
        s += __shfl_down(s, off, 64);

    __shared__ float lds[4];
    if (lane == 0) lds[wave] = s;
    __syncthreads();
    if (tid == 0) {
        float tot = lds[0] + lds[1] + lds[2] + lds[3];
        // masked-out zeros clamp up to 1e-12 in the reference: B*(C-1) of them
        tot += (float)B_ROWS * (float)(C_CLASSES - 1) * 1e-12f;
        out[0] = tot / (float)B_ROWS;
    }
}

extern "C" void kernel_launch(void* const* d_in, const int* in_sizes, int n_in,
                              void* d_out, int out_size, void* d_ws, size_t ws_size,
                              hipStream_t stream) {
    const float* x       = (const float*)d_in[0];
    const int*   labels  = (const int*)d_in[1];
    const float* centers = (const float*)d_in[2];
    float*       out     = (float*)d_out;
    float*       partials = (float*)d_ws;   // S1_BLOCKS floats = 8 KB

    center_loss_stage1<<<S1_BLOCKS, 256, 0, stream>>>(x, labels, centers, partials);
    center_loss_stage2<<<1, 256, 0, stream>>>(partials, out);
}